// Round 2
// baseline (1080.291 us; speedup 1.0000x reference)
//
#include <hip/hip_runtime.h>
#include <hip/hip_bf16.h>

using bf16 = __hip_bfloat16;

constexpr int N   = 50000;
constexpr int E   = 800000;
constexpr int NIN = 300;
constexpr int H   = 4;
constexpr int C   = 64;
constexpr int HC  = H * C;      // 256
constexpr int G   = 256;
constexpr int NOUT = 768;

__device__ __forceinline__ float b2f(bf16 v) { return __bfloat162float(v); }
__device__ __forceinline__ float us2f(unsigned short u) {
    bf16 b; *(unsigned short*)&b = u; return __bfloat162float(b);
}
__device__ __forceinline__ unsigned short f2us(float f) {
    bf16 b = __float2bfloat16(f); return *(unsigned short*)&b;
}
__device__ __forceinline__ float lrelu_att(float v) { return v > 0.f ? v : 0.2f * v; }
__device__ __forceinline__ float lrelu_act(float v) { return v > 0.f ? v : 0.01f * v; }

// generic input load: isbf chooses bf16 vs fp32 interpretation
__device__ __forceinline__ float ldin(const void* p, int isbf, size_t i) {
    return isbf ? b2f(((const bf16*)p)[i]) : ((const float*)p)[i];
}

// ---------------- dtype detection ----------------
__global__ void k_detect(const unsigned short* __restrict__ xr, int* __restrict__ flag) {
    __shared__ int cnt_s;
    if (threadIdx.x == 0) cnt_s = 0;
    __syncthreads();
    unsigned short u = xr[threadIdx.x];           // first 256 uint16s of x
    int ex = (u >> 7) & 0xFF;
    int ok = (ex == 0) || (ex >= 100 && ex <= 140);
    atomicAdd(&cnt_s, ok);
    __syncthreads();
    if (threadIdx.x == 0) *flag = (cnt_s >= 240) ? 1 : 0;  // 1 = bf16 inputs
}

// ---------------- zero init (cnt) ----------------
__global__ void k_zero(int* __restrict__ p, int n) {
    int i = blockIdx.x * 256 + threadIdx.x;
    if (i < n) p[i] = 0;
}

// ---------------- h = x @ lin_w  (fp32 accum), store bf16 ----------------
constexpr int BM = 64;
constexpr int BKK = 30;  // 300 = 10 * 30
__global__ __launch_bounds__(256) void k_lin(const void* __restrict__ x,
                                             const void* __restrict__ w,
                                             bf16* __restrict__ hb,
                                             const int* __restrict__ flag) {
    __shared__ float xs[BM][BKK + 1];
    __shared__ float wsh[BKK][HC];
    int isbf = *flag;
    int t = threadIdx.x;
    int tx = t & 15, ty = t >> 4;
    int row0 = blockIdx.x * BM;
    float acc[4][16];
#pragma unroll
    for (int i = 0; i < 4; i++)
#pragma unroll
        for (int j = 0; j < 16; j++) acc[i][j] = 0.f;

    for (int kc = 0; kc < NIN; kc += BKK) {
        for (int idx = t; idx < BM * BKK; idx += 256) {
            int r = idx / BKK, c = idx - r * BKK;
            int gr = row0 + r;
            xs[r][c] = (gr < N) ? ldin(x, isbf, (size_t)gr * NIN + kc + c) : 0.f;
        }
#pragma unroll
        for (int i = 0; i < BKK; i++) {
            wsh[i][t] = ldin(w, isbf, (size_t)(kc + i) * HC + t);
        }
        __syncthreads();
#pragma unroll
        for (int k = 0; k < BKK; k++) {
            float xv[4];
#pragma unroll
            for (int i = 0; i < 4; i++) xv[i] = xs[ty * 4 + i][k];
            float wv[16];
#pragma unroll
            for (int j = 0; j < 16; j++) wv[j] = wsh[k][tx + 16 * j];
#pragma unroll
            for (int i = 0; i < 4; i++)
#pragma unroll
                for (int j = 0; j < 16; j++) acc[i][j] += xv[i] * wv[j];
        }
        __syncthreads();
    }
#pragma unroll
    for (int i = 0; i < 4; i++) {
        int gr = row0 + ty * 4 + i;
        if (gr < N) {
#pragma unroll
            for (int j = 0; j < 16; j++)
                hb[(size_t)gr * HC + tx + 16 * j] = __float2bfloat16(acc[i][j]);
        }
    }
}

// ---------------- per-node attention dots ----------------
__global__ __launch_bounds__(256) void k_att(const bf16* __restrict__ hb,
                                             const void* __restrict__ att_s,
                                             const void* __restrict__ att_d,
                                             float* __restrict__ a_src,
                                             float* __restrict__ a_dst,
                                             const int* __restrict__ flag) {
    int isbf = *flag;
    int n = blockIdx.x;
    int t = threadIdx.x;
    float v = b2f(hb[(size_t)n * HC + t]);
    float ps = v * ldin(att_s, isbf, t);
    float pd = v * ldin(att_d, isbf, t);
#pragma unroll
    for (int off = 32; off; off >>= 1) {
        ps += __shfl_down(ps, off, 64);
        pd += __shfl_down(pd, off, 64);
    }
    int lane = t & 63;
    int head = t >> 6;
    if (lane == 0) {
        a_src[n * H + head] = ps;
        a_dst[n * H + head] = pd;
    }
}

// ---------------- degree histogram ----------------
__global__ void k_hist(const int* __restrict__ dst, int* __restrict__ cnt) {
    int e = blockIdx.x * 256 + threadIdx.x;
    if (e < E) atomicAdd(&cnt[dst[e]], 1);
}

// ---------------- exclusive scan (one block) ----------------
__global__ __launch_bounds__(1024) void k_scan(const int* __restrict__ cnt,
                                               int* __restrict__ off,
                                               int* __restrict__ cur) {
    __shared__ int part[1024];
    int t = threadIdx.x;
    const int CH = (N + 1023) / 1024;  // 49
    int base = t * CH;
    int s = 0;
    for (int i = 0; i < CH; i++) {
        int idx = base + i;
        if (idx < N) s += cnt[idx];
    }
    part[t] = s;
    __syncthreads();
    for (int d = 1; d < 1024; d <<= 1) {
        int v = (t >= d) ? part[t - d] : 0;
        __syncthreads();
        part[t] += v;
        __syncthreads();
    }
    int run = (t == 0) ? 0 : part[t - 1];
    for (int i = 0; i < CH; i++) {
        int idx = base + i;
        if (idx < N) {
            off[idx] = run;
            cur[idx] = run;
            run += cnt[idx];
        }
    }
    if (t == 1023) off[N] = part[1023];
}

// ---------------- scatter edges into CSR ----------------
__global__ void k_scatter(const int* __restrict__ ei,
                          int* __restrict__ cur,
                          int* __restrict__ csr_s) {
    int e = blockIdx.x * 256 + threadIdx.x;
    if (e >= E) return;
    int s = ei[e], d = ei[E + e];
    int pos = atomicAdd(&cur[d], 1);
    csr_s[pos] = s;
}

// ---------------- per-node aggregation (one wave per node) ----------------
__global__ __launch_bounds__(256) void k_agg(const bf16* __restrict__ hb,
                                             const float* __restrict__ a_src,
                                             const float* __restrict__ a_dst,
                                             const int* __restrict__ off,
                                             const int* __restrict__ csr_s,
                                             const void* __restrict__ bias,
                                             bf16* __restrict__ outn,
                                             const int* __restrict__ flag) {
    int isbf = *flag;
    int wave = threadIdx.x >> 6, lane = threadIdx.x & 63;
    int n = blockIdx.x * 4 + wave;
    if (n >= N) return;
    int head = lane >> 4;
    float adv = a_dst[n * 4 + head];
    float wself = __expf(lrelu_att(a_src[n * 4 + head] + adv));
    const unsigned short* hrow = (const unsigned short*)hb;
    ushort4 hv = *(const ushort4*)&hrow[(size_t)n * HC + lane * 4];
    float4 acc;
    acc.x = us2f(hv.x) * wself;
    acc.y = us2f(hv.y) * wself;
    acc.z = us2f(hv.z) * wself;
    acc.w = us2f(hv.w) * wself;
    float ssum = wself;
    int p0 = off[n], p1 = off[n + 1];
    for (int p = p0; p < p1; p++) {
        int s = csr_s[p];
        float wv = __expf(lrelu_att(a_src[s * 4 + head] + adv));
        ushort4 hs = *(const ushort4*)&hrow[(size_t)s * HC + lane * 4];
        acc.x += us2f(hs.x) * wv;
        acc.y += us2f(hs.y) * wv;
        acc.z += us2f(hs.z) * wv;
        acc.w += us2f(hs.w) * wv;
        ssum += wv;
    }
    float inv = 1.f / ssum;
    ushort4 o;
    o.x = f2us(lrelu_act(acc.x * inv + ldin(bias, isbf, lane * 4 + 0)));
    o.y = f2us(lrelu_act(acc.y * inv + ldin(bias, isbf, lane * 4 + 1)));
    o.z = f2us(lrelu_act(acc.z * inv + ldin(bias, isbf, lane * 4 + 2)));
    o.w = f2us(lrelu_act(acc.w * inv + ldin(bias, isbf, lane * 4 + 3)));
    *(ushort4*)&((unsigned short*)outn)[(size_t)n * HC + lane * 4] = o;
}

// ---------------- graph start offsets (batch sorted) ----------------
__global__ void k_ranges(const int* __restrict__ batch, int* __restrict__ gs) {
    int g = threadIdx.x;  // 256 threads
    int lo = 0, hi = N;
    while (lo < hi) {
        int mid = (lo + hi) >> 1;
        if (batch[mid] < g) lo = mid + 1;
        else hi = mid;
    }
    gs[g] = lo;
    if (g == 0) gs[G] = N;
}

// ---------------- mean pool ----------------
__global__ __launch_bounds__(256) void k_pool(const bf16* __restrict__ outn,
                                              const int* __restrict__ gs,
                                              float* __restrict__ pooled) {
    int g = blockIdx.x, t = threadIdx.x;
    int s = gs[g], e2 = gs[g + 1];
    const unsigned short* on = (const unsigned short*)outn;
    float acc = 0.f;
    for (int n = s; n < e2; n++) acc += us2f(on[(size_t)n * HC + t]);
    float cntf = (float)((e2 - s) > 1 ? (e2 - s) : 1);
    pooled[g * HC + t] = acc / cntf;
}

// ---------------- final FC (dual-dtype output) ----------------
__global__ __launch_bounds__(256) void k_fc(const float* __restrict__ pooled,
                                            const void* __restrict__ fw,
                                            const void* __restrict__ fb,
                                            void* __restrict__ out,
                                            const int* __restrict__ flag) {
    __shared__ float pl[HC];
    int isbf = *flag;
    int g = blockIdx.y;
    int o = blockIdx.x * 256 + threadIdx.x;
    pl[threadIdx.x] = pooled[g * HC + threadIdx.x];
    __syncthreads();
    float acc = ldin(fb, isbf, o);
#pragma unroll 8
    for (int k = 0; k < HC; k++) acc += pl[k] * ldin(fw, isbf, (size_t)k * NOUT + o);
    size_t oi = (size_t)g * NOUT + o;
    if (isbf) ((bf16*)out)[oi] = __float2bfloat16(acc);
    else      ((float*)out)[oi] = acc;
}

extern "C" void kernel_launch(void* const* d_in, const int* in_sizes, int n_in,
                              void* d_out, int out_size, void* d_ws, size_t ws_size,
                              hipStream_t stream) {
    const void* x     = d_in[0];
    const int*  ei    = (const int*)d_in[1];
    const int*  batch = (const int*)d_in[2];
    const void* lin_w = d_in[3];
    const void* att_s = d_in[4];
    const void* att_d = d_in[5];
    const void* bias  = d_in[6];
    const void* fc1w  = d_in[7];
    const void* fc1b  = d_in[8];

    char* p = (char*)d_ws;
    bf16* hb      = (bf16*)p;  p += (size_t)N * HC * 2;   // 25.6 MB
    float* a_src  = (float*)p; p += (size_t)N * H * 4;    // 0.8 MB
    float* a_dst  = (float*)p; p += (size_t)N * H * 4;
    int* cnt      = (int*)p;   p += (size_t)N * 4;
    int* off      = (int*)p;   p += (size_t)(N + 4) * 4;
    int* cur      = (int*)p;   p += (size_t)N * 4;
    int* csr_s    = (int*)p;   p += (size_t)E * 4;        // 3.2 MB
    bf16* outn    = (bf16*)p;  p += (size_t)N * HC * 2;   // 25.6 MB
    int* gs       = (int*)p;   p += (size_t)(G + 4) * 4;
    float* pooled = (float*)p; p += (size_t)G * HC * 4;
    int* flag     = (int*)p;   p += 16;

    k_detect<<<1, 256, 0, stream>>>((const unsigned short*)x, flag);
    k_zero<<<(N + 255) / 256, 256, 0, stream>>>(cnt, N);
    k_lin<<<(N + BM - 1) / BM, 256, 0, stream>>>(x, lin_w, hb, flag);
    k_att<<<N, 256, 0, stream>>>(hb, att_s, att_d, a_src, a_dst, flag);
    k_hist<<<(E + 255) / 256, 256, 0, stream>>>(ei + E, cnt);
    k_scan<<<1, 1024, 0, stream>>>(cnt, off, cur);
    k_scatter<<<(E + 255) / 256, 256, 0, stream>>>(ei, cur, csr_s);
    k_agg<<<(N + 3) / 4, 256, 0, stream>>>(hb, a_src, a_dst, off, csr_s, bias, outn, flag);
    k_ranges<<<1, G, 0, stream>>>(batch, gs);
    k_pool<<<G, HC, 0, stream>>>(outn, gs, pooled);
    k_fc<<<dim3(NOUT / 256, G), 256, 0, stream>>>(pooled, fc1w, fc1b, d_out, flag);
}

// Round 3
// 459.472 us; speedup vs baseline: 2.3512x; 2.3512x over previous
//
#include <hip/hip_runtime.h>
#include <hip/hip_bf16.h>

using bf16 = __hip_bfloat16;
typedef __attribute__((ext_vector_type(8))) short short8;
typedef __attribute__((ext_vector_type(4))) float f32x4;

constexpr int N   = 50000;
constexpr int E   = 800000;
constexpr int NIN = 300;
constexpr int H   = 4;
constexpr int C   = 64;
constexpr int HC  = H * C;      // 256
constexpr int G   = 256;
constexpr int NOUT = 768;
constexpr int KP  = 320;        // K padded to 10*32
constexpr int NKB = 10;         // K blocks of 32
constexpr int MP  = 50048;      // M padded to 782*64

__device__ __forceinline__ float b2f(bf16 v) { return __bfloat162float(v); }
__device__ __forceinline__ float us2f(unsigned short u) {
    bf16 b; *(unsigned short*)&b = u; return __bfloat162float(b);
}
__device__ __forceinline__ unsigned short f2us(float f) {
    bf16 b = __float2bfloat16(f); return *(unsigned short*)&b;
}
__device__ __forceinline__ float lrelu_att(float v) { return v > 0.f ? v : 0.2f * v; }
__device__ __forceinline__ float lrelu_act(float v) { return v > 0.f ? v : 0.01f * v; }
__device__ __forceinline__ float ldin(const void* p, int isbf, size_t i) {
    return isbf ? b2f(((const bf16*)p)[i]) : ((const float*)p)[i];
}

// ---------------- dtype detection (unchanged, verified R2) ----------------
__global__ void k_detect(const unsigned short* __restrict__ xr, int* __restrict__ flag) {
    __shared__ int cnt_s;
    if (threadIdx.x == 0) cnt_s = 0;
    __syncthreads();
    unsigned short u = xr[threadIdx.x];
    int ex = (u >> 7) & 0xFF;
    int ok = (ex == 0) || (ex >= 100 && ex <= 140);
    atomicAdd(&cnt_s, ok);
    __syncthreads();
    if (threadIdx.x == 0) *flag = (cnt_s >= 240) ? 1 : 0;  // 1 = bf16 inputs
}

__global__ void k_zero(int* __restrict__ p, int n) {
    int i = blockIdx.x * 256 + threadIdx.x;
    if (i < n) p[i] = 0;
}

// ---------------- x -> padded bf16 xb[MP][KP] ----------------
__global__ __launch_bounds__(256) void k_cvt_x(const void* __restrict__ x,
                                               unsigned short* __restrict__ xb,
                                               const int* __restrict__ flag) {
    int isbf = *flag;
    unsigned int tid = blockIdx.x * 256 + threadIdx.x;
    unsigned int idx = tid * 4;                 // element index in xb (row*KP+col)
    if (idx >= (unsigned int)MP * KP) return;
    int row = idx / KP;
    int col = idx - row * KP;
    ushort4 o;
    if (row >= N || col >= NIN) {               // NIN%4==0: a 4-group is all-in or all-out
        o = make_ushort4(0, 0, 0, 0);
    } else {
        size_t src = (size_t)row * NIN + col;
        if (isbf) {
            o = *(const ushort4*)((const unsigned short*)x + src);
        } else {
            float4 f = *(const float4*)((const float*)x + src);
            o = make_ushort4(f2us(f.x), f2us(f.y), f2us(f.z), f2us(f.w));
        }
    }
    *(ushort4*)(xb + idx) = o;
}

// ---------------- lin_w -> MFMA-B-fragment swizzled bswz[kb*16+nb][lane][8] ----------------
__global__ void k_swz_w(const void* __restrict__ w, unsigned short* __restrict__ bswz,
                        const int* __restrict__ flag) {
    int isbf = *flag;
    int b = blockIdx.x;           // kb*16+nb
    int kb = b >> 4, nb = b & 15;
    int lane = threadIdx.x;       // 64
    int q = lane >> 4, cl = lane & 15;
    int n = nb * 16 + cl;
    unsigned short v[8];
#pragma unroll
    for (int j = 0; j < 8; j++) {
        int k = kb * 32 + q * 8 + j;
        float f = (k < NIN) ? ldin(w, isbf, (size_t)k * HC + n) : 0.f;
        v[j] = f2us(f);
    }
    ushort4* dst = (ushort4*)(bswz + ((size_t)b * 64 + lane) * 8);
    dst[0] = make_ushort4(v[0], v[1], v[2], v[3]);
    dst[1] = make_ushort4(v[4], v[5], v[6], v[7]);
}

// ---------------- h = x @ lin_w via MFMA 16x16x32 bf16 ----------------
// wave = 16-row strip x full 256 cols; A-frags in regs for all K; B coalesced 16B/lane.
__global__ __launch_bounds__(256) void k_lin_mfma(const unsigned short* __restrict__ xb,
                                                  const unsigned short* __restrict__ bswz,
                                                  unsigned short* __restrict__ hb) {
    int wave = threadIdx.x >> 6, lane = threadIdx.x & 63;
    int q = lane >> 4, cl = lane & 15;
    int m0 = blockIdx.x * 64 + wave * 16;
    const unsigned short* arow = xb + (size_t)(m0 + cl) * KP + q * 8;
    short8 a[NKB];
#pragma unroll
    for (int kb = 0; kb < NKB; kb++) a[kb] = *(const short8*)(arow + kb * 32);
    f32x4 acc[16];
#pragma unroll
    for (int nb = 0; nb < 16; nb++) acc[nb] = f32x4{0.f, 0.f, 0.f, 0.f};
#pragma unroll
    for (int kb = 0; kb < NKB; kb++) {
#pragma unroll
        for (int nb = 0; nb < 16; nb++) {
            short8 bfr = *(const short8*)(bswz + ((size_t)(kb * 16 + nb) * 64 + lane) * 8);
            acc[nb] = __builtin_amdgcn_mfma_f32_16x16x32_bf16(a[kb], bfr, acc[nb], 0, 0, 0);
        }
    }
#pragma unroll
    for (int nb = 0; nb < 16; nb++) {
#pragma unroll
        for (int r = 0; r < 4; r++) {
            int gm = m0 + q * 4 + r;
            if (gm < N) hb[(size_t)gm * HC + nb * 16 + cl] = f2us(acc[nb][r]);
        }
    }
}

// ---------------- per-node attention dots ----------------
__global__ __launch_bounds__(256) void k_att(const unsigned short* __restrict__ hb,
                                             const void* __restrict__ att_s,
                                             const void* __restrict__ att_d,
                                             float* __restrict__ a_src,
                                             float* __restrict__ a_dst,
                                             const int* __restrict__ flag) {
    int isbf = *flag;
    int n = blockIdx.x;
    int t = threadIdx.x;
    float v = us2f(hb[(size_t)n * HC + t]);
    float ps = v * ldin(att_s, isbf, t);
    float pd = v * ldin(att_d, isbf, t);
#pragma unroll
    for (int off = 32; off; off >>= 1) {
        ps += __shfl_down(ps, off, 64);
        pd += __shfl_down(pd, off, 64);
    }
    if ((t & 63) == 0) {
        a_src[n * H + (t >> 6)] = ps;
        a_dst[n * H + (t >> 6)] = pd;
    }
}

// ---------------- degree histogram ----------------
__global__ void k_hist(const int* __restrict__ dst, int* __restrict__ cnt) {
    int e = blockIdx.x * 256 + threadIdx.x;
    if (e < E) atomicAdd(&cnt[dst[e]], 1);
}

// ---------------- 3-phase coalesced scan ----------------
__global__ __launch_bounds__(256) void k_scan1(const int* __restrict__ cnt, int* __restrict__ bsum) {
    __shared__ int wsum[4];
    int idx = blockIdx.x * 256 + threadIdx.x;
    int v = (idx < N) ? cnt[idx] : 0;
#pragma unroll
    for (int o2 = 32; o2; o2 >>= 1) v += __shfl_down(v, o2, 64);
    if ((threadIdx.x & 63) == 0) wsum[threadIdx.x >> 6] = v;
    __syncthreads();
    if (threadIdx.x == 0) bsum[blockIdx.x] = wsum[0] + wsum[1] + wsum[2] + wsum[3];
}

__global__ __launch_bounds__(256) void k_scan2(const int* __restrict__ bsum, int* __restrict__ boff,
                                               int* __restrict__ off, int nb) {
    __shared__ int sd[256];
    int t = threadIdx.x;
    int v = (t < nb) ? bsum[t] : 0;
    sd[t] = v;
    __syncthreads();
    for (int d = 1; d < 256; d <<= 1) {
        int u = (t >= d) ? sd[t - d] : 0;
        __syncthreads();
        sd[t] += u;
        __syncthreads();
    }
    if (t < nb) boff[t] = sd[t] - v;
    if (t == 255) off[N] = sd[255];
}

__global__ __launch_bounds__(256) void k_scan3(const int* __restrict__ cnt, const int* __restrict__ boff,
                                               int* __restrict__ off, int* __restrict__ cur) {
    __shared__ int sd[256];
    int t = threadIdx.x;
    int idx = blockIdx.x * 256 + t;
    int v = (idx < N) ? cnt[idx] : 0;
    sd[t] = v;
    __syncthreads();
    for (int d = 1; d < 256; d <<= 1) {
        int u = (t >= d) ? sd[t - d] : 0;
        __syncthreads();
        sd[t] += u;
        __syncthreads();
    }
    int ex = sd[t] - v + boff[blockIdx.x];
    if (idx < N) { off[idx] = ex; cur[idx] = ex; }
}

// ---------------- scatter edges into CSR ----------------
__global__ void k_scatter(const int* __restrict__ ei, int* __restrict__ cur, int* __restrict__ csr_s) {
    int e = blockIdx.x * 256 + threadIdx.x;
    if (e >= E) return;
    int s = ei[e], d = ei[E + e];
    int pos = atomicAdd(&cur[d], 1);
    csr_s[pos] = s;
}

// ---------------- per-node aggregation, unroll-4 for MLP ----------------
__global__ __launch_bounds__(256) void k_agg(const unsigned short* __restrict__ hb,
                                             const float* __restrict__ a_src,
                                             const float* __restrict__ a_dst,
                                             const int* __restrict__ off,
                                             const int* __restrict__ csr_s,
                                             const void* __restrict__ bias,
                                             unsigned short* __restrict__ outn,
                                             const int* __restrict__ flag) {
    int isbf = *flag;
    int wave = threadIdx.x >> 6, lane = threadIdx.x & 63;
    int n = blockIdx.x * 4 + wave;
    if (n >= N) return;
    int head = lane >> 4;
    float adv = a_dst[n * 4 + head];
    float wself = __expf(lrelu_att(a_src[n * 4 + head] + adv));
    ushort4 hv = *(const ushort4*)&hb[(size_t)n * HC + lane * 4];
    float4 acc;
    acc.x = us2f(hv.x) * wself;
    acc.y = us2f(hv.y) * wself;
    acc.z = us2f(hv.z) * wself;
    acc.w = us2f(hv.w) * wself;
    float ssum = wself;
    int p0 = off[n], p1 = off[n + 1];
    int p = p0;
    for (; p + 4 <= p1; p += 4) {
        int s0 = csr_s[p + 0], s1 = csr_s[p + 1], s2 = csr_s[p + 2], s3 = csr_s[p + 3];
        ushort4 g0 = *(const ushort4*)&hb[(size_t)s0 * HC + lane * 4];
        ushort4 g1 = *(const ushort4*)&hb[(size_t)s1 * HC + lane * 4];
        ushort4 g2 = *(const ushort4*)&hb[(size_t)s2 * HC + lane * 4];
        ushort4 g3 = *(const ushort4*)&hb[(size_t)s3 * HC + lane * 4];
        float w0 = __expf(lrelu_att(a_src[s0 * 4 + head] + adv));
        float w1 = __expf(lrelu_att(a_src[s1 * 4 + head] + adv));
        float w2 = __expf(lrelu_att(a_src[s2 * 4 + head] + adv));
        float w3 = __expf(lrelu_att(a_src[s3 * 4 + head] + adv));
        acc.x += us2f(g0.x) * w0 + us2f(g1.x) * w1 + us2f(g2.x) * w2 + us2f(g3.x) * w3;
        acc.y += us2f(g0.y) * w0 + us2f(g1.y) * w1 + us2f(g2.y) * w2 + us2f(g3.y) * w3;
        acc.z += us2f(g0.z) * w0 + us2f(g1.z) * w1 + us2f(g2.z) * w2 + us2f(g3.z) * w3;
        acc.w += us2f(g0.w) * w0 + us2f(g1.w) * w1 + us2f(g2.w) * w2 + us2f(g3.w) * w3;
        ssum += w0 + w1 + w2 + w3;
    }
    for (; p < p1; p++) {
        int s = csr_s[p];
        float wv = __expf(lrelu_att(a_src[s * 4 + head] + adv));
        ushort4 hs = *(const ushort4*)&hb[(size_t)s * HC + lane * 4];
        acc.x += us2f(hs.x) * wv;
        acc.y += us2f(hs.y) * wv;
        acc.z += us2f(hs.z) * wv;
        acc.w += us2f(hs.w) * wv;
        ssum += wv;
    }
    float inv = 1.f / ssum;
    ushort4 o;
    o.x = f2us(lrelu_act(acc.x * inv + ldin(bias, isbf, lane * 4 + 0)));
    o.y = f2us(lrelu_act(acc.y * inv + ldin(bias, isbf, lane * 4 + 1)));
    o.z = f2us(lrelu_act(acc.z * inv + ldin(bias, isbf, lane * 4 + 2)));
    o.w = f2us(lrelu_act(acc.w * inv + ldin(bias, isbf, lane * 4 + 3)));
    *(ushort4*)&outn[(size_t)n * HC + lane * 4] = o;
}

// ---------------- graph start offsets (batch sorted) ----------------
__global__ void k_ranges(const int* __restrict__ batch, int* __restrict__ gs) {
    int g = threadIdx.x;
    int lo = 0, hi = N;
    while (lo < hi) {
        int mid = (lo + hi) >> 1;
        if (batch[mid] < g) lo = mid + 1;
        else hi = mid;
    }
    gs[g] = lo;
    if (g == 0) gs[G] = N;
}

// ---------------- pooling phase A: coalesced row accumulation ----------------
__global__ __launch_bounds__(256) void k_pool_sum(const unsigned short* __restrict__ outn,
                                                  const int* __restrict__ batch,
                                                  float* __restrict__ sums) {
    int t = threadIdx.x;
    int r0 = blockIdx.x * 256;
    int r1 = r0 + 256 < N ? r0 + 256 : N;
    int curg = batch[r0];
    float acc = 0.f;
    for (int r = r0; r < r1; r++) {
        int g = batch[r];
        if (g != curg) {
            atomicAdd(&sums[(size_t)curg * HC + t], acc);
            acc = 0.f;
            curg = g;
        }
        acc += us2f(outn[(size_t)r * HC + t]);
    }
    atomicAdd(&sums[(size_t)curg * HC + t], acc);
}

// ---------------- final FC (mean-divide folded in) ----------------
__global__ __launch_bounds__(256) void k_fc(const float* __restrict__ sums,
                                            const int* __restrict__ gs,
                                            const void* __restrict__ fw,
                                            const void* __restrict__ fb,
                                            void* __restrict__ out,
                                            const int* __restrict__ flag) {
    __shared__ float pl[HC];
    int isbf = *flag;
    int g = blockIdx.y;
    int o = blockIdx.x * 256 + threadIdx.x;
    int c = gs[g + 1] - gs[g];
    float inv = 1.f / (float)(c > 1 ? c : 1);
    pl[threadIdx.x] = sums[(size_t)g * HC + threadIdx.x] * inv;
    __syncthreads();
    float acc = ldin(fb, isbf, o);
#pragma unroll 8
    for (int k = 0; k < HC; k++) acc += pl[k] * ldin(fw, isbf, (size_t)k * NOUT + o);
    size_t oi = (size_t)g * NOUT + o;
    if (isbf) ((bf16*)out)[oi] = __float2bfloat16(acc);
    else      ((float*)out)[oi] = acc;
}

extern "C" void kernel_launch(void* const* d_in, const int* in_sizes, int n_in,
                              void* d_out, int out_size, void* d_ws, size_t ws_size,
                              hipStream_t stream) {
    const void* x     = d_in[0];
    const int*  ei    = (const int*)d_in[1];
    const int*  batch = (const int*)d_in[2];
    const void* lin_w = d_in[3];
    const void* att_s = d_in[4];
    const void* att_d = d_in[5];
    const void* bias  = d_in[6];
    const void* fc1w  = d_in[7];
    const void* fc1b  = d_in[8];

    char* p = (char*)d_ws;
    unsigned short* xb = (unsigned short*)p; p += (size_t)MP * KP * 2;   // 32.0 MB (aliased as outn later)
    unsigned short* hb = (unsigned short*)p; p += (size_t)N * HC * 2;    // 25.6 MB
    float* a_src  = (float*)p; p += (size_t)N * H * 4;
    float* a_dst  = (float*)p; p += (size_t)N * H * 4;
    int* cnt      = (int*)p;   p += (size_t)N * 4;                       // cnt+sums zeroed together
    float* sums   = (float*)p; p += (size_t)G * HC * 4;
    int* off      = (int*)p;   p += (size_t)(N + 4) * 4;
    int* cur      = (int*)p;   p += (size_t)N * 4;
    int* csr_s    = (int*)p;   p += (size_t)E * 4;
    unsigned short* bswz = (unsigned short*)p; p += (size_t)160 * 64 * 8 * 2;
    int* bsum     = (int*)p;   p += 1024;
    int* boff     = (int*)p;   p += 1024;
    int* gs       = (int*)p;   p += (size_t)(G + 4) * 4;
    int* flag     = (int*)p;   p += 16;
    unsigned short* outn = xb;   // alias: xb dead after k_lin_mfma, outn born at k_agg

    const int NB = (N + 255) / 256;  // 196

    k_detect<<<1, 256, 0, stream>>>((const unsigned short*)x, flag);
    k_zero<<<(N + G * HC + 255) / 256, 256, 0, stream>>>(cnt, N + G * HC);
    k_cvt_x<<<(MP * KP / 4 + 255) / 256, 256, 0, stream>>>(x, xb, flag);
    k_swz_w<<<160, 64, 0, stream>>>(lin_w, bswz, flag);
    k_lin_mfma<<<MP / 64, 256, 0, stream>>>(xb, bswz, hb);
    k_att<<<N, 256, 0, stream>>>(hb, att_s, att_d, a_src, a_dst, flag);
    k_hist<<<(E + 255) / 256, 256, 0, stream>>>(ei + E, cnt);
    k_scan1<<<NB, 256, 0, stream>>>(cnt, bsum);
    k_scan2<<<1, 256, 0, stream>>>(bsum, boff, off, NB);
    k_scan3<<<NB, 256, 0, stream>>>(cnt, boff, off, cur);
    k_scatter<<<(E + 255) / 256, 256, 0, stream>>>(ei, cur, csr_s);
    k_agg<<<(N + 3) / 4, 256, 0, stream>>>(hb, a_src, a_dst, off, csr_s, bias, outn, flag);
    k_ranges<<<1, G, 0, stream>>>(batch, gs);
    k_pool_sum<<<NB, 256, 0, stream>>>(outn, batch, sums);
    k_fc<<<dim3(NOUT / 256, G), 256, 0, stream>>>(sums, fc1w ? gs : gs, fc1w, fc1b, d_out, flag);
}

// Round 4
// 359.251 us; speedup vs baseline: 3.0071x; 1.2790x over previous
//
#include <hip/hip_runtime.h>
#include <hip/hip_bf16.h>

using bf16 = __hip_bfloat16;
typedef __attribute__((ext_vector_type(8))) short short8;
typedef __attribute__((ext_vector_type(4))) float f32x4;

constexpr int N   = 50000;
constexpr int E   = 800000;
constexpr int NIN = 300;
constexpr int H   = 4;
constexpr int C   = 64;
constexpr int HC  = H * C;      // 256
constexpr int G   = 256;
constexpr int NOUT = 768;
constexpr int KP  = 320;        // K padded to 10*32
constexpr int NKB = 10;         // K blocks of 32
constexpr int MP  = 50048;      // M padded to 782*64

__device__ __forceinline__ float b2f(bf16 v) { return __bfloat162float(v); }
__device__ __forceinline__ float us2f(unsigned short u) {
    bf16 b; *(unsigned short*)&b = u; return __bfloat162float(b);
}
__device__ __forceinline__ unsigned short f2us(float f) {
    bf16 b = __float2bfloat16(f); return *(unsigned short*)&b;
}
__device__ __forceinline__ float lrelu_att(float v) { return v > 0.f ? v : 0.2f * v; }
__device__ __forceinline__ float lrelu_act(float v) { return v > 0.f ? v : 0.01f * v; }
__device__ __forceinline__ float ldin(const void* p, int isbf, size_t i) {
    return isbf ? b2f(((const bf16*)p)[i]) : ((const float*)p)[i];
}

// ---------------- init: zero cnt+sums, block 0 also dtype-detects ----------------
__global__ __launch_bounds__(256) void k_init(const unsigned short* __restrict__ xr,
                                              int* __restrict__ flag,
                                              int* __restrict__ zp, int nz) {
    int i = blockIdx.x * 256 + threadIdx.x;
    if (i < nz) zp[i] = 0;
    if (blockIdx.x == 0) {
        __shared__ int cnt_s;
        if (threadIdx.x == 0) cnt_s = 0;
        __syncthreads();
        unsigned short u = xr[threadIdx.x];
        int ex = (u >> 7) & 0xFF;
        int ok = (ex == 0) || (ex >= 100 && ex <= 140);
        atomicAdd(&cnt_s, ok);
        __syncthreads();
        if (threadIdx.x == 0) *flag = (cnt_s >= 240) ? 1 : 0;  // 1 = bf16 inputs
    }
}

// ---------------- x -> padded bf16 xb[MP][KP]; tail blocks swizzle lin_w ----------------
constexpr int NCVT = (MP * KP / 4 + 255) / 256;   // 15644
__global__ __launch_bounds__(256) void k_cvt_sw(const void* __restrict__ x,
                                                const void* __restrict__ w,
                                                unsigned short* __restrict__ xb,
                                                unsigned short* __restrict__ bswz,
                                                const int* __restrict__ flag) {
    int isbf = *flag;
    if (blockIdx.x < NCVT) {
        unsigned int tid = blockIdx.x * 256 + threadIdx.x;
        unsigned int idx = tid * 4;
        if (idx >= (unsigned int)MP * KP) return;
        int row = idx / KP;
        int col = idx - row * KP;
        ushort4 o;
        if (row >= N || col >= NIN) {
            o = make_ushort4(0, 0, 0, 0);
        } else {
            size_t src = (size_t)row * NIN + col;
            if (isbf) {
                o = *(const ushort4*)((const unsigned short*)x + src);
            } else {
                float4 f = *(const float4*)((const float*)x + src);
                o = make_ushort4(f2us(f.x), f2us(f.y), f2us(f.z), f2us(f.w));
            }
        }
        *(ushort4*)(xb + idx) = o;
    } else {
        int b = (blockIdx.x - NCVT) * 4 + (threadIdx.x >> 6);   // kb*16+nb, 0..159
        if (b >= 160) return;
        int kb = b >> 4, nb = b & 15;
        int lane = threadIdx.x & 63;
        int q = lane >> 4, cl = lane & 15;
        int n = nb * 16 + cl;
        unsigned short v[8];
#pragma unroll
        for (int j = 0; j < 8; j++) {
            int k = kb * 32 + q * 8 + j;
            float f = (k < NIN) ? ldin(w, isbf, (size_t)k * HC + n) : 0.f;
            v[j] = f2us(f);
        }
        ushort4* dst = (ushort4*)(bswz + ((size_t)b * 64 + lane) * 8);
        dst[0] = make_ushort4(v[0], v[1], v[2], v[3]);
        dst[1] = make_ushort4(v[4], v[5], v[6], v[7]);
    }
}

// ---------------- h = x @ lin_w via MFMA; att dots fused in epilogue ----------------
__global__ __launch_bounds__(256) void k_lin_mfma(const unsigned short* __restrict__ xb,
                                                  const unsigned short* __restrict__ bswz,
                                                  const void* __restrict__ att_s,
                                                  const void* __restrict__ att_d,
                                                  unsigned short* __restrict__ hb,
                                                  float* __restrict__ a_src,
                                                  float* __restrict__ a_dst,
                                                  const int* __restrict__ flag) {
    int isbf = *flag;
    int wave = threadIdx.x >> 6, lane = threadIdx.x & 63;
    int q = lane >> 4, cl = lane & 15;
    int m0 = blockIdx.x * 64 + wave * 16;
    const unsigned short* arow = xb + (size_t)(m0 + cl) * KP + q * 8;
    short8 a[NKB];
#pragma unroll
    for (int kb = 0; kb < NKB; kb++) a[kb] = *(const short8*)(arow + kb * 32);
    f32x4 acc[16];
#pragma unroll
    for (int nb = 0; nb < 16; nb++) acc[nb] = f32x4{0.f, 0.f, 0.f, 0.f};
#pragma unroll
    for (int kb = 0; kb < NKB; kb++) {
#pragma unroll
        for (int nb = 0; nb < 16; nb++) {
            short8 bfr = *(const short8*)(bswz + ((size_t)(kb * 16 + nb) * 64 + lane) * 8);
            acc[nb] = __builtin_amdgcn_mfma_f32_16x16x32_bf16(a[kb], bfr, acc[nb], 0, 0, 0);
        }
    }
    // epilogue: store h (bf16) + per-head attention partials
    float ps[4][4], pd[4][4];   // [h][r]
#pragma unroll
    for (int hh = 0; hh < 4; hh++)
#pragma unroll
        for (int r = 0; r < 4; r++) { ps[hh][r] = 0.f; pd[hh][r] = 0.f; }
#pragma unroll
    for (int nb = 0; nb < 16; nb++) {
        float as_ = ldin(att_s, isbf, nb * 16 + cl);
        float ad_ = ldin(att_d, isbf, nb * 16 + cl);
        int hh = nb >> 2;
#pragma unroll
        for (int r = 0; r < 4; r++) {
            float v = acc[nb][r];
            ps[hh][r] += v * as_;
            pd[hh][r] += v * ad_;
            int gm = m0 + q * 4 + r;
            if (gm < N) hb[(size_t)gm * HC + nb * 16 + cl] = f2us(v);
        }
    }
#pragma unroll
    for (int hh = 0; hh < 4; hh++) {
#pragma unroll
        for (int r = 0; r < 4; r++) {
            float vs = ps[hh][r], vd = pd[hh][r];
#pragma unroll
            for (int m = 1; m < 16; m <<= 1) {
                vs += __shfl_xor(vs, m, 64);
                vd += __shfl_xor(vd, m, 64);
            }
            int gm = m0 + q * 4 + r;
            if (cl == 0 && gm < N) {
                a_src[gm * 4 + hh] = vs;
                a_dst[gm * 4 + hh] = vd;
            }
        }
    }
}

// ---------------- degree histogram ----------------
__global__ void k_hist(const int* __restrict__ dst, int* __restrict__ cnt) {
    int e = blockIdx.x * 256 + threadIdx.x;
    if (e < E) atomicAdd(&cnt[dst[e]], 1);
}

// ---------------- 3-phase coalesced scan (+graph ranges folded into phase 2) ----------------
__global__ __launch_bounds__(256) void k_scan1(const int* __restrict__ cnt, int* __restrict__ bsum) {
    __shared__ int wsum[4];
    int idx = blockIdx.x * 256 + threadIdx.x;
    int v = (idx < N) ? cnt[idx] : 0;
#pragma unroll
    for (int o2 = 32; o2; o2 >>= 1) v += __shfl_down(v, o2, 64);
    if ((threadIdx.x & 63) == 0) wsum[threadIdx.x >> 6] = v;
    __syncthreads();
    if (threadIdx.x == 0) bsum[blockIdx.x] = wsum[0] + wsum[1] + wsum[2] + wsum[3];
}

__global__ __launch_bounds__(256) void k_scan2r(const int* __restrict__ bsum, int* __restrict__ boff,
                                                int* __restrict__ off, int nb,
                                                const int* __restrict__ batch, int* __restrict__ gs) {
    __shared__ int sd[256];
    int t = threadIdx.x;
    int v = (t < nb) ? bsum[t] : 0;
    sd[t] = v;
    __syncthreads();
    for (int d = 1; d < 256; d <<= 1) {
        int u = (t >= d) ? sd[t - d] : 0;
        __syncthreads();
        sd[t] += u;
        __syncthreads();
    }
    if (t < nb) boff[t] = sd[t] - v;
    if (t == 255) off[N] = sd[255];
    // graph start offsets (batch is sorted)
    int lo = 0, hi = N;
    while (lo < hi) {
        int mid = (lo + hi) >> 1;
        if (batch[mid] < t) lo = mid + 1;
        else hi = mid;
    }
    gs[t] = lo;
    if (t == 0) gs[G] = N;
}

__global__ __launch_bounds__(256) void k_scan3(const int* __restrict__ cnt, const int* __restrict__ boff,
                                               int* __restrict__ off, int* __restrict__ cur) {
    __shared__ int sd[256];
    int t = threadIdx.x;
    int idx = blockIdx.x * 256 + t;
    int v = (idx < N) ? cnt[idx] : 0;
    sd[t] = v;
    __syncthreads();
    for (int d = 1; d < 256; d <<= 1) {
        int u = (t >= d) ? sd[t - d] : 0;
        __syncthreads();
        sd[t] += u;
        __syncthreads();
    }
    int ex = sd[t] - v + boff[blockIdx.x];
    if (idx < N) { off[idx] = ex; cur[idx] = ex; }
}

// ---------------- scatter edges into CSR ----------------
__global__ void k_scatter(const int* __restrict__ ei, int* __restrict__ cur, int* __restrict__ csr_s) {
    int e = blockIdx.x * 256 + threadIdx.x;
    if (e >= E) return;
    int s = ei[e], d = ei[E + e];
    int pos = atomicAdd(&cur[d], 1);
    csr_s[pos] = s;
}

// ---------------- per-node aggregation, unroll-4 + index prefetch ----------------
__global__ __launch_bounds__(256) void k_agg(const unsigned short* __restrict__ hb,
                                             const float* __restrict__ a_src,
                                             const float* __restrict__ a_dst,
                                             const int* __restrict__ off,
                                             const int* __restrict__ csr_s,
                                             const void* __restrict__ bias,
                                             unsigned short* __restrict__ outn,
                                             const int* __restrict__ flag) {
    int isbf = *flag;
    int wave = threadIdx.x >> 6, lane = threadIdx.x & 63;
    int n = blockIdx.x * 4 + wave;
    if (n >= N) return;
    int head = lane >> 4;
    float adv = a_dst[n * 4 + head];
    float wself = __expf(lrelu_att(a_src[n * 4 + head] + adv));
    ushort4 hv = *(const ushort4*)&hb[(size_t)n * HC + lane * 4];
    float4 acc;
    acc.x = us2f(hv.x) * wself;
    acc.y = us2f(hv.y) * wself;
    acc.z = us2f(hv.z) * wself;
    acc.w = us2f(hv.w) * wself;
    float ssum = wself;
    int p0 = off[n], p1 = off[n + 1];
    int i0 = 0, i1 = 0, i2 = 0, i3 = 0;
    if (p0 + 4 <= p1) { i0 = csr_s[p0]; i1 = csr_s[p0 + 1]; i2 = csr_s[p0 + 2]; i3 = csr_s[p0 + 3]; }
    int p = p0;
    for (; p + 4 <= p1; p += 4) {
        int s0 = i0, s1 = i1, s2 = i2, s3 = i3;
        ushort4 g0 = *(const ushort4*)&hb[(size_t)s0 * HC + lane * 4];
        ushort4 g1 = *(const ushort4*)&hb[(size_t)s1 * HC + lane * 4];
        ushort4 g2 = *(const ushort4*)&hb[(size_t)s2 * HC + lane * 4];
        ushort4 g3 = *(const ushort4*)&hb[(size_t)s3 * HC + lane * 4];
        float w0 = __expf(lrelu_att(a_src[s0 * 4 + head] + adv));
        float w1 = __expf(lrelu_att(a_src[s1 * 4 + head] + adv));
        float w2 = __expf(lrelu_att(a_src[s2 * 4 + head] + adv));
        float w3 = __expf(lrelu_att(a_src[s3 * 4 + head] + adv));
        int nn = p + 4;
        if (nn + 4 <= p1) { i0 = csr_s[nn]; i1 = csr_s[nn + 1]; i2 = csr_s[nn + 2]; i3 = csr_s[nn + 3]; }
        acc.x += us2f(g0.x) * w0 + us2f(g1.x) * w1 + us2f(g2.x) * w2 + us2f(g3.x) * w3;
        acc.y += us2f(g0.y) * w0 + us2f(g1.y) * w1 + us2f(g2.y) * w2 + us2f(g3.y) * w3;
        acc.z += us2f(g0.z) * w0 + us2f(g1.z) * w1 + us2f(g2.z) * w2 + us2f(g3.z) * w3;
        acc.w += us2f(g0.w) * w0 + us2f(g1.w) * w1 + us2f(g2.w) * w2 + us2f(g3.w) * w3;
        ssum += w0 + w1 + w2 + w3;
    }
    for (; p < p1; p++) {
        int s = csr_s[p];
        float wv = __expf(lrelu_att(a_src[s * 4 + head] + adv));
        ushort4 hs = *(const ushort4*)&hb[(size_t)s * HC + lane * 4];
        acc.x += us2f(hs.x) * wv;
        acc.y += us2f(hs.y) * wv;
        acc.z += us2f(hs.z) * wv;
        acc.w += us2f(hs.w) * wv;
        ssum += wv;
    }
    float inv = 1.f / ssum;
    ushort4 o;
    o.x = f2us(lrelu_act(acc.x * inv + ldin(bias, isbf, lane * 4 + 0)));
    o.y = f2us(lrelu_act(acc.y * inv + ldin(bias, isbf, lane * 4 + 1)));
    o.z = f2us(lrelu_act(acc.z * inv + ldin(bias, isbf, lane * 4 + 2)));
    o.w = f2us(lrelu_act(acc.w * inv + ldin(bias, isbf, lane * 4 + 3)));
    *(ushort4*)&outn[(size_t)n * HC + lane * 4] = o;
}

// ---------------- pooling: (graph, quarter) grid, unroll-4, one atomic per thread ----------------
__global__ __launch_bounds__(256) void k_pool2(const unsigned short* __restrict__ outn,
                                               const int* __restrict__ gs,
                                               float* __restrict__ sums) {
    int g = blockIdx.x, qq = blockIdx.y, t = threadIdx.x;
    int s = gs[g], e2 = gs[g + 1];
    int len = e2 - s;
    int r0 = s + (len * qq) / 4;
    int r1 = s + (len * (qq + 1)) / 4;
    float a0 = 0.f, a1 = 0.f, a2 = 0.f, a3 = 0.f;
    int r = r0;
    for (; r + 4 <= r1; r += 4) {
        a0 += us2f(outn[(size_t)(r + 0) * HC + t]);
        a1 += us2f(outn[(size_t)(r + 1) * HC + t]);
        a2 += us2f(outn[(size_t)(r + 2) * HC + t]);
        a3 += us2f(outn[(size_t)(r + 3) * HC + t]);
    }
    for (; r < r1; r++) a0 += us2f(outn[(size_t)r * HC + t]);
    float v = (a0 + a1) + (a2 + a3);
    if (r1 > r0) atomicAdd(&sums[(size_t)g * HC + t], v);
}

// ---------------- final FC (mean-divide folded in) ----------------
__global__ __launch_bounds__(256) void k_fc(const float* __restrict__ sums,
                                            const int* __restrict__ gs,
                                            const void* __restrict__ fw,
                                            const void* __restrict__ fb,
                                            void* __restrict__ out,
                                            const int* __restrict__ flag) {
    __shared__ float pl[HC];
    int isbf = *flag;
    int g = blockIdx.y;
    int o = blockIdx.x * 256 + threadIdx.x;
    int c = gs[g + 1] - gs[g];
    float inv = 1.f / (float)(c > 1 ? c : 1);
    pl[threadIdx.x] = sums[(size_t)g * HC + threadIdx.x] * inv;
    __syncthreads();
    float acc = ldin(fb, isbf, o);
#pragma unroll 8
    for (int k = 0; k < HC; k++) acc += pl[k] * ldin(fw, isbf, (size_t)k * NOUT + o);
    size_t oi = (size_t)g * NOUT + o;
    if (isbf) ((bf16*)out)[oi] = __float2bfloat16(acc);
    else      ((float*)out)[oi] = acc;
}

extern "C" void kernel_launch(void* const* d_in, const int* in_sizes, int n_in,
                              void* d_out, int out_size, void* d_ws, size_t ws_size,
                              hipStream_t stream) {
    const void* x     = d_in[0];
    const int*  ei    = (const int*)d_in[1];
    const int*  batch = (const int*)d_in[2];
    const void* lin_w = d_in[3];
    const void* att_s = d_in[4];
    const void* att_d = d_in[5];
    const void* bias  = d_in[6];
    const void* fc1w  = d_in[7];
    const void* fc1b  = d_in[8];

    char* p = (char*)d_ws;
    unsigned short* xb = (unsigned short*)p; p += (size_t)MP * KP * 2;   // 32.0 MB (aliased as outn)
    unsigned short* hb = (unsigned short*)p; p += (size_t)N * HC * 2;    // 25.6 MB
    float* a_src  = (float*)p; p += (size_t)N * H * 4;
    float* a_dst  = (float*)p; p += (size_t)N * H * 4;
    int* cnt      = (int*)p;   p += (size_t)N * 4;                       // cnt+sums zeroed together
    float* sums   = (float*)p; p += (size_t)G * HC * 4;
    int* off      = (int*)p;   p += (size_t)(N + 4) * 4;
    int* cur      = (int*)p;   p += (size_t)N * 4;
    int* csr_s    = (int*)p;   p += (size_t)E * 4;
    unsigned short* bswz = (unsigned short*)p; p += (size_t)160 * 64 * 8 * 2;
    int* bsum     = (int*)p;   p += 1024;
    int* boff     = (int*)p;   p += 1024;
    int* gs       = (int*)p;   p += (size_t)(G + 4) * 4;
    int* flag     = (int*)p;   p += 16;
    unsigned short* outn = xb;   // alias: xb dead after k_lin_mfma, outn born at k_agg

    const int NB = (N + 255) / 256;  // 196
    const int NZ = N + G * HC;

    k_init<<<(NZ + 255) / 256, 256, 0, stream>>>((const unsigned short*)x, flag, cnt, NZ);
    k_cvt_sw<<<NCVT + 40, 256, 0, stream>>>(x, lin_w, xb, bswz, flag);
    k_lin_mfma<<<MP / 64, 256, 0, stream>>>(xb, bswz, att_s, att_d, hb, a_src, a_dst, flag);
    k_hist<<<(E + 255) / 256, 256, 0, stream>>>(ei + E, cnt);
    k_scan1<<<NB, 256, 0, stream>>>(cnt, bsum);
    k_scan2r<<<1, 256, 0, stream>>>(bsum, boff, off, NB, batch, gs);
    k_scan3<<<NB, 256, 0, stream>>>(cnt, boff, off, cur);
    k_scatter<<<(E + 255) / 256, 256, 0, stream>>>(ei, cur, csr_s);
    k_agg<<<(N + 3) / 4, 256, 0, stream>>>(hb, a_src, a_dst, off, csr_s, bias, outn, flag);
    k_pool2<<<dim3(G, 4), 256, 0, stream>>>(outn, gs, sums);
    k_fc<<<dim3(NOUT / 256, G), 256, 0, stream>>>(sums, gs, fc1w, fc1b, d_out, flag);
}